// Round 1
// baseline (188.033 us; speedup 1.0000x reference)
//
#include <hip/hip_runtime.h>

#define HH 64
#define WW 64
#define CC 128
#define FF 256
#define NTAP 9
#define KD 1152   // NTAP*CC

typedef __attribute__((ext_vector_type(8))) short bf16x8;
typedef __attribute__((ext_vector_type(4))) float floatx4;

// Faithful tap order from np.stack(np.meshgrid(arange(3),arange(3),indexing='ij')).reshape(-1,2)
__device__ __constant__ int c_iy[9] = {0,0,1,2,2,1,0,2,1};
__device__ __constant__ int c_ix[9] = {0,1,1,2,0,2,1,0,2};

__device__ inline unsigned short f2bf(float v) {
  union { float f; unsigned u; } c; c.f = v;
  unsigned r = (c.u + 0x7FFFu + ((c.u >> 16) & 1u)) >> 16;  // RNE
  return (unsigned short)r;
}

// W (1152 x 256 fp32, [k][f] row-major)  ->  Wt (256 x 1152 bf16, [f][k])
__global__ void wt_prep_kernel(const float* __restrict__ W, unsigned short* __restrict__ Wt) {
  int idx = blockIdx.x * 256 + threadIdx.x;   // 0 .. 294911
  int k = idx >> 8;
  int f = idx & 255;
  Wt[f * KD + k] = f2bf(W[idx]);
}

__global__ __launch_bounds__(256, 2) void dconv_kernel(
    const float* __restrict__ X, const float* __restrict__ Off,
    const unsigned short* __restrict__ Wt, const float* __restrict__ bias,
    float* __restrict__ Out)
{
  // mapped tile: 64 positions x 128 channels, bf16, +8 pad (row=136) to break bank conflicts
  __shared__ unsigned short smA[64 * 136];

  const int blk  = blockIdx.x;      // 0..511 : blk = b*64 + y
  const int b    = blk >> 6;
  const int y    = blk & 63;
  const int tid  = threadIdx.x;
  const int wave = tid >> 6;
  const int lane = tid & 63;
  const int sp   = tid >> 2;        // staging position 0..63 (the x column)
  const int scg  = (tid & 3) << 5;  // staging channel group base: 0,32,64,96

  const float* xb     = X + (size_t)b * (HH * WW * CC);
  const float* offRow = Off + (size_t)(b * HH + y) * (WW * 2 * NTAP);

  floatx4 acc[4][4];
#pragma unroll
  for (int i = 0; i < 4; ++i)
#pragma unroll
    for (int j = 0; j < 4; ++j)
      acc[i][j] = (floatx4){0.f, 0.f, 0.f, 0.f};

  const int arow = lane & 15;   // A m index / B f index (within 16)
  const int aq   = lane >> 4;   // quad: k = aq*8 + j

  for (int n = 0; n < NTAP; ++n) {
    // ---- stage mapped[64][128] (bf16) into LDS: bilinear sample ----
    {
      float2 off2 = *(const float2*)(offRow + sp * (2 * NTAP) + 2 * n);
      float cy = (float)(y  - 1 + c_iy[n]) + off2.x;
      float cx = (float)(sp - 1 + c_ix[n]) + off2.y;
      cy = fminf(fmaxf(cy, 0.f), 63.f);
      cx = fminf(fmaxf(cx, 0.f), 63.f);
      float fy0 = floorf(cy), fy1 = ceilf(cy);
      float fx0 = floorf(cx), fx1 = ceilf(cx);
      int y0 = (int)fy0, y1 = (int)fy1, x0 = (int)fx0, x1 = (int)fx1;
      float fy = cy - fy0;
      float fx = cx - fx0;
      const float4* p00 = (const float4*)(xb + (y0 * WW + x0) * CC + scg); // lt
      const float4* p10 = (const float4*)(xb + (y1 * WW + x0) * CC + scg); // rt (y1,x0)
      const float4* p01 = (const float4*)(xb + (y0 * WW + x1) * CC + scg); // lb (y0,x1)
      const float4* p11 = (const float4*)(xb + (y1 * WW + x1) * CC + scg); // rb
      unsigned short* dst = &smA[sp * 136 + scg];
#pragma unroll
      for (int i = 0; i < 8; ++i) {
        float4 v00 = p00[i], v10 = p10[i], v01 = p01[i], v11 = p11[i];
        float tx, tb, m0, m1, m2, m3;
        tx = v00.x + (v10.x - v00.x) * fy;
        tb = v01.x + (v11.x - v01.x) * fy;
        m0 = tx + (tb - tx) * fx;
        tx = v00.y + (v10.y - v00.y) * fy;
        tb = v01.y + (v11.y - v01.y) * fy;
        m1 = tx + (tb - tx) * fx;
        tx = v00.z + (v10.z - v00.z) * fy;
        tb = v01.z + (v11.z - v01.z) * fy;
        m2 = tx + (tb - tx) * fx;
        tx = v00.w + (v10.w - v00.w) * fy;
        tb = v01.w + (v11.w - v01.w) * fy;
        m3 = tx + (tb - tx) * fx;
        ushort4 pk;
        pk.x = f2bf(m0); pk.y = f2bf(m1); pk.z = f2bf(m2); pk.w = f2bf(m3);
        *(ushort4*)(dst + i * 4) = pk;
      }
    }
    __syncthreads();

    const unsigned short* wn = Wt + n * CC;
#pragma unroll
    for (int ks = 0; ks < 4; ++ks) {
      const int k0 = ks * 32;
      bf16x8 afr[4], bfr[4];
#pragma unroll
      for (int mt = 0; mt < 4; ++mt)
        afr[mt] = *(const bf16x8*)&smA[(mt * 16 + arow) * 136 + k0 + aq * 8];
#pragma unroll
      for (int ft = 0; ft < 4; ++ft) {
        const int f = wave * 64 + ft * 16 + arow;
        bfr[ft] = *(const bf16x8*)(wn + (size_t)f * KD + k0 + aq * 8);
      }
#pragma unroll
      for (int mt = 0; mt < 4; ++mt)
#pragma unroll
        for (int ft = 0; ft < 4; ++ft)
          acc[mt][ft] = __builtin_amdgcn_mfma_f32_16x16x32_bf16(afr[mt], bfr[ft], acc[mt][ft], 0, 0, 0);
    }
    __syncthreads();
  }

  // ---- epilogue: D layout col=lane&15, row=quad*4+reg ----
  float* outBlk = Out + (size_t)blk * 64 * FF;
  float bvals[4];
#pragma unroll
  for (int ft = 0; ft < 4; ++ft)
    bvals[ft] = bias[wave * 64 + ft * 16 + arow];
#pragma unroll
  for (int mt = 0; mt < 4; ++mt) {
#pragma unroll
    for (int ft = 0; ft < 4; ++ft) {
      const int f = wave * 64 + ft * 16 + arow;
#pragma unroll
      for (int r = 0; r < 4; ++r) {
        const int m = mt * 16 + aq * 4 + r;
        outBlk[m * FF + f] = acc[mt][ft][r] + bvals[ft];
      }
    }
  }
}

extern "C" void kernel_launch(void* const* d_in, const int* in_sizes, int n_in,
                              void* d_out, int out_size, void* d_ws, size_t ws_size,
                              hipStream_t stream) {
  const float* X    = (const float*)d_in[0];
  const float* Off  = (const float*)d_in[1];
  const float* W    = (const float*)d_in[2];
  const float* bias = (const float*)d_in[3];
  float* Out = (float*)d_out;
  unsigned short* Wt = (unsigned short*)d_ws;   // 256*1152 bf16 = 589824 B

  wt_prep_kernel<<<(KD * FF) / 256, 256, 0, stream>>>(W, Wt);
  dconv_kernel<<<512, 256, 0, stream>>>(X, Off, Wt, bias, Out);
}

// Round 2
// 185.848 us; speedup vs baseline: 1.0118x; 1.0118x over previous
//
#include <hip/hip_runtime.h>

#define HH 64
#define WW 64
#define CC 128
#define FF 256
#define NTAP 9
#define KD 1152   // NTAP*CC
#define MROW 32   // positions per block
#define LROW 136  // LDS row stride in shorts (128 + 8 pad)

typedef __attribute__((ext_vector_type(8))) short bf16x8;
typedef __attribute__((ext_vector_type(4))) float floatx4;

// Faithful tap order from np.stack(np.meshgrid(arange(3),arange(3),indexing='ij')).reshape(-1,2)
__device__ __constant__ int c_iy[9] = {0,0,1,2,2,1,0,2,1};
__device__ __constant__ int c_ix[9] = {0,1,1,2,0,2,1,0,2};

__device__ inline unsigned short f2bf(float v) {
  union { float f; unsigned u; } c; c.f = v;
  unsigned r = (c.u + 0x7FFFu + ((c.u >> 16) & 1u)) >> 16;  // RNE
  return (unsigned short)r;
}

// W (1152 x 256 fp32, [k][f]) -> Wt (256 x 1152 bf16, [f][k])
__global__ void wt_prep_kernel(const float* __restrict__ W, unsigned short* __restrict__ Wt) {
  int idx = blockIdx.x * 256 + threadIdx.x;
  int k = idx >> 8;
  int f = idx & 255;
  Wt[f * KD + k] = f2bf(W[idx]);
}

// Issue the 16 corner loads (4 corners x 16ch) for tap n into registers.
__device__ inline void gather_tap(const float* __restrict__ xb,
                                  const float* __restrict__ offRow,
                                  int y, int sp, int scg, int n,
                                  float4 pre[4][4], float& fy, float& fx) {
  float2 off2 = *(const float2*)(offRow + sp * (2 * NTAP) + 2 * n);
  float cy = (float)(y  - 1 + c_iy[n]) + off2.x;
  float cx = (float)(sp - 1 + c_ix[n]) + off2.y;
  cy = fminf(fmaxf(cy, 0.f), 63.f);
  cx = fminf(fmaxf(cx, 0.f), 63.f);
  float fy0 = floorf(cy), fy1 = ceilf(cy);
  float fx0 = floorf(cx), fx1 = ceilf(cx);
  int y0 = (int)fy0, y1 = (int)fy1, x0 = (int)fx0, x1 = (int)fx1;
  fy = cy - fy0;
  fx = cx - fx0;
  const float4* p00 = (const float4*)(xb + (y0 * WW + x0) * CC + scg); // lt
  const float4* p10 = (const float4*)(xb + (y1 * WW + x0) * CC + scg); // rt (y1,x0)
  const float4* p01 = (const float4*)(xb + (y0 * WW + x1) * CC + scg); // lb (y0,x1)
  const float4* p11 = (const float4*)(xb + (y1 * WW + x1) * CC + scg); // rb
#pragma unroll
  for (int ci = 0; ci < 4; ++ci) {
    pre[ci][0] = p00[ci];
    pre[ci][1] = p10[ci];
    pre[ci][2] = p01[ci];
    pre[ci][3] = p11[ci];
  }
}

// Bilinear combine + bf16 pack + LDS store (16 channels).
__device__ inline void interp_store(unsigned short* dst, const float4 pre[4][4],
                                    float fy, float fx) {
#pragma unroll
  for (int ci = 0; ci < 4; ++ci) {
    float4 v00 = pre[ci][0], v10 = pre[ci][1], v01 = pre[ci][2], v11 = pre[ci][3];
    float tx, tb;
    ushort4 pk;
    tx = v00.x + (v10.x - v00.x) * fy;
    tb = v01.x + (v11.x - v01.x) * fy;
    pk.x = f2bf(tx + (tb - tx) * fx);
    tx = v00.y + (v10.y - v00.y) * fy;
    tb = v01.y + (v11.y - v01.y) * fy;
    pk.y = f2bf(tx + (tb - tx) * fx);
    tx = v00.z + (v10.z - v00.z) * fy;
    tb = v01.z + (v11.z - v01.z) * fy;
    pk.z = f2bf(tx + (tb - tx) * fx);
    tx = v00.w + (v10.w - v00.w) * fy;
    tb = v01.w + (v11.w - v01.w) * fy;
    pk.w = f2bf(tx + (tb - tx) * fx);
    *(ushort4*)(dst + ci * 4) = pk;
  }
}

__global__ __launch_bounds__(256, 3) void dconv_kernel(
    const float* __restrict__ X, const float* __restrict__ Off,
    const unsigned short* __restrict__ Wt, const float* __restrict__ bias,
    float* __restrict__ Out)
{
  __shared__ unsigned short smA[2][MROW * LROW];

  // XCD-locality swizzle: blk = idx*8 + b  =>  blk%8 == b (one batch per XCD)
  const int blk  = blockIdx.x;       // 0..1023
  const int b    = blk & 7;
  const int idx  = blk >> 3;         // 0..127
  const int y    = idx >> 1;         // 0..63
  const int half = idx & 1;          // which 32-column half of the row
  const int tid  = threadIdx.x;
  const int wave = tid >> 6;
  const int lane = tid & 63;
  const int spl  = tid >> 3;         // local position 0..31
  const int sp   = half * 32 + spl;  // global x position
  const int scg  = (tid & 7) * 16;   // channel base: 16 ch per thread

  const float* xb     = X + (size_t)b * (HH * WW * CC);
  const float* offRow = Off + (size_t)(b * HH + y) * (WW * 2 * NTAP);

  floatx4 acc[2][4];
#pragma unroll
  for (int i = 0; i < 2; ++i)
#pragma unroll
    for (int j = 0; j < 4; ++j)
      acc[i][j] = (floatx4){0.f, 0.f, 0.f, 0.f};

  const int arow = lane & 15;  // A m index / B f index (within 16)
  const int aq   = lane >> 4;  // quad: k = aq*8 + j

  float4 pre[4][4];
  float pfy, pfx;

  // Pre-stage tap 0
  gather_tap(xb, offRow, y, sp, scg, 0, pre, pfy, pfx);
  interp_store(&smA[0][spl * LROW + scg], pre, pfy, pfx);
  __syncthreads();

  for (int n = 0; n < NTAP; ++n) {
    const int cur = n & 1, nxt = cur ^ 1;

    // Prefetch tap n+1 corner data into registers (latency hides under MFMA)
    if (n + 1 < NTAP)
      gather_tap(xb, offRow, y, sp, scg, n + 1, pre, pfy, pfx);

    // MFMA on current buffer
    const unsigned short* wn = Wt + n * CC;
#pragma unroll
    for (int ks = 0; ks < 4; ++ks) {
      const int k0 = ks * 32;
      bf16x8 afr[2], bfr[4];
      afr[0] = *(const bf16x8*)&smA[cur][(arow)      * LROW + k0 + aq * 8];
      afr[1] = *(const bf16x8*)&smA[cur][(16 + arow) * LROW + k0 + aq * 8];
#pragma unroll
      for (int ft = 0; ft < 4; ++ft) {
        const int f = wave * 64 + ft * 16 + arow;
        bfr[ft] = *(const bf16x8*)(wn + (size_t)f * KD + k0 + aq * 8);
      }
#pragma unroll
      for (int mt = 0; mt < 2; ++mt)
#pragma unroll
        for (int ft = 0; ft < 4; ++ft)
          acc[mt][ft] = __builtin_amdgcn_mfma_f32_16x16x32_bf16(afr[mt], bfr[ft], acc[mt][ft], 0, 0, 0);
    }

    // Combine + store into the other buffer
    if (n + 1 < NTAP)
      interp_store(&smA[nxt][spl * LROW + scg], pre, pfy, pfx);
    __syncthreads();
  }

  // Epilogue: D layout col=lane&15, row=quad*4+reg
  float* outRow = Out + ((size_t)(b * HH + y) * WW + half * 32) * FF;
  float bvals[4];
#pragma unroll
  for (int ft = 0; ft < 4; ++ft)
    bvals[ft] = bias[wave * 64 + ft * 16 + arow];
#pragma unroll
  for (int mt = 0; mt < 2; ++mt) {
#pragma unroll
    for (int ft = 0; ft < 4; ++ft) {
      const int f = wave * 64 + ft * 16 + arow;
#pragma unroll
      for (int r = 0; r < 4; ++r) {
        const int m = mt * 16 + aq * 4 + r;
        outRow[m * FF + f] = acc[mt][ft][r] + bvals[ft];
      }
    }
  }
}

extern "C" void kernel_launch(void* const* d_in, const int* in_sizes, int n_in,
                              void* d_out, int out_size, void* d_ws, size_t ws_size,
                              hipStream_t stream) {
  const float* X    = (const float*)d_in[0];
  const float* Off  = (const float*)d_in[1];
  const float* W    = (const float*)d_in[2];
  const float* bias = (const float*)d_in[3];
  float* Out = (float*)d_out;
  unsigned short* Wt = (unsigned short*)d_ws;  // 256*1152 bf16 = 589824 B

  wt_prep_kernel<<<(KD * FF) / 256, 256, 0, stream>>>(W, Wt);
  dconv_kernel<<<1024, 256, 0, stream>>>(X, Off, Wt, bias, Out);
}

// Round 3
// 163.241 us; speedup vs baseline: 1.1519x; 1.1385x over previous
//
#include <hip/hip_runtime.h>

#define HH 64
#define WW 64
#define CC 128
#define FF 256
#define NTAP 9
#define KD 1152   // NTAP*CC
#define MTOT 32768

typedef __attribute__((ext_vector_type(8))) short bf16x8;
typedef __attribute__((ext_vector_type(4))) float floatx4;

// Faithful tap order from np.stack(np.meshgrid(arange(3),arange(3),indexing='ij')).reshape(-1,2)
__device__ __constant__ int c_iy[9] = {0,0,1,2,2,1,0,2,1};
__device__ __constant__ int c_ix[9] = {0,1,1,2,0,2,1,0,2};

__device__ inline unsigned short f2bf(float v) {
  union { float f; unsigned u; } c; c.f = v;
  unsigned r = (c.u + 0x7FFFu + ((c.u >> 16) & 1u)) >> 16;  // RNE
  return (unsigned short)r;
}

// W (1152 x 256 fp32, [k][f]) -> Wt (256 x 1152 bf16, [f][k])
__global__ void wt_prep_kernel(const float* __restrict__ W, unsigned short* __restrict__ Wt) {
  int idx = blockIdx.x * 256 + threadIdx.x;
  int k = idx >> 8;
  int f = idx & 255;
  Wt[f * KD + k] = f2bf(W[idx]);
}

// ---------------- Kernel A: bilinear gather/interp producer ----------------
// One thread = one (pos, tap, 16-channel chunk). Output: Mp[pos][k=n*128+c] bf16.
__global__ __launch_bounds__(256, 3) void interp_kernel(
    const float* __restrict__ X, const float* __restrict__ Off,
    unsigned short* __restrict__ Mp)
{
  const int blk   = blockIdx.x;          // 0..9215
  const int b     = blk & 7;             // batch -> XCD locality
  const int inner = blk >> 3;            // 0..1151
  const unsigned t = inner * 256u + threadIdx.x;  // 0..294911 within batch
  const int chunk = t & 7;
  const unsigned i = t >> 3;             // pos_local*9 + n
  const unsigned pos_local = i / 9u;
  const int n = (int)(i - pos_local * 9u);
  const int y = (int)(pos_local >> 6);
  const int x = (int)(pos_local & 63u);
  const int scg = chunk * 16;            // channel base

  const float* xb = X + (size_t)b * (HH * WW * CC);
  float2 off2 = *(const float2*)(Off + ((size_t)(b * HH + y) * WW + x) * (2 * NTAP) + 2 * n);

  float cy = (float)(y - 1 + c_iy[n]) + off2.x;
  float cx = (float)(x - 1 + c_ix[n]) + off2.y;
  cy = fminf(fmaxf(cy, 0.f), 63.f);
  cx = fminf(fmaxf(cx, 0.f), 63.f);
  float fy0 = floorf(cy), fy1 = ceilf(cy);
  float fx0 = floorf(cx), fx1 = ceilf(cx);
  int y0 = (int)fy0, y1 = (int)fy1, x0 = (int)fx0, x1 = (int)fx1;
  float fy = cy - fy0;
  float fx = cx - fx0;

  const float4* p00 = (const float4*)(xb + (y0 * WW + x0) * CC + scg); // lt
  const float4* p10 = (const float4*)(xb + (y1 * WW + x0) * CC + scg); // rt (y1,x0)
  const float4* p01 = (const float4*)(xb + (y0 * WW + x1) * CC + scg); // lb (y0,x1)
  const float4* p11 = (const float4*)(xb + (y1 * WW + x1) * CC + scg); // rb

  bf16x8 out0, out1;
#pragma unroll
  for (int ci = 0; ci < 4; ++ci) {
    float4 v00 = p00[ci], v10 = p10[ci], v01 = p01[ci], v11 = p11[ci];
    float tx, tb, m;
    unsigned short r[4];
    tx = v00.x + (v10.x - v00.x) * fy;
    tb = v01.x + (v11.x - v01.x) * fy;
    m = tx + (tb - tx) * fx; r[0] = f2bf(m);
    tx = v00.y + (v10.y - v00.y) * fy;
    tb = v01.y + (v11.y - v01.y) * fy;
    m = tx + (tb - tx) * fx; r[1] = f2bf(m);
    tx = v00.z + (v10.z - v00.z) * fy;
    tb = v01.z + (v11.z - v01.z) * fy;
    m = tx + (tb - tx) * fx; r[2] = f2bf(m);
    tx = v00.w + (v10.w - v00.w) * fy;
    tb = v01.w + (v11.w - v01.w) * fy;
    m = tx + (tb - tx) * fx; r[3] = f2bf(m);
    if (ci < 2) {
      out0[ci * 4 + 0] = (short)r[0]; out0[ci * 4 + 1] = (short)r[1];
      out0[ci * 4 + 2] = (short)r[2]; out0[ci * 4 + 3] = (short)r[3];
    } else {
      out1[(ci - 2) * 4 + 0] = (short)r[0]; out1[(ci - 2) * 4 + 1] = (short)r[1];
      out1[(ci - 2) * 4 + 2] = (short)r[2]; out1[(ci - 2) * 4 + 3] = (short)r[3];
    }
  }

  unsigned short* dst = Mp + (size_t)(b * 4096 + pos_local) * KD + n * CC + scg;
  *(bf16x8*)dst = out0;
  *(bf16x8*)(dst + 8) = out1;
}

// ---------------- Kernel B: GEMM 32768 x 1152 x 256 (bf16 -> fp32) ----------------
// Block: 128M x 128F, 4 waves (each 64M x 64F). Double-buffered LDS, async staging,
// XOR chunk swizzle for conflict-free ds_read_b128.
__global__ __launch_bounds__(256, 2) void gemm_kernel(
    const unsigned short* __restrict__ Mp, const unsigned short* __restrict__ Wt,
    const float* __restrict__ bias, float* __restrict__ Out)
{
  __shared__ unsigned short smA[2][128 * 64];
  __shared__ unsigned short smB[2][128 * 64];

  const int blk = blockIdx.x;            // 0..511
  const int mb = blk >> 1, fb = blk & 1;
  const int m0 = mb * 128, f0 = fb * 128;
  const int tid = threadIdx.x;
  const int wave = tid >> 6, lane = tid & 63;
  const int wm = (wave >> 1) * 64;       // wave M offset in block
  const int wf = (wave & 1) * 64;        // wave F offset in block
  const int arow = lane & 15, aq = lane >> 4;

  const int srow = tid >> 3;             // staging: 32 rows per pass
  const int sch = tid & 7;               // 8 chunks of 16B per 64-k row

  floatx4 acc[4][4];
#pragma unroll
  for (int i2 = 0; i2 < 4; ++i2)
#pragma unroll
    for (int j2 = 0; j2 < 4; ++j2)
      acc[i2][j2] = (floatx4){0.f, 0.f, 0.f, 0.f};

#define STAGE(SM, SRC, ROW0, BUF, K0)                                              \
  {                                                                                \
    _Pragma("unroll")                                                              \
    for (int p = 0; p < 4; ++p) {                                                  \
      int row = p * 32 + srow;                                                     \
      int chp = sch ^ (row & 7);                                                   \
      const unsigned short* g = (SRC) + (size_t)((ROW0) + row) * KD + (K0) + chp * 8; \
      unsigned short* l = &SM[BUF][row * 64 + sch * 8];                            \
      __builtin_amdgcn_global_load_lds(                                            \
          (const __attribute__((address_space(1))) unsigned int*)g,                \
          (__attribute__((address_space(3))) unsigned int*)l, 16, 0, 0);           \
    }                                                                              \
  }

  // Prologue: stage k-tile 0 into buf 0
  STAGE(smA, Mp, m0, 0, 0)
  STAGE(smB, Wt, f0, 0, 0)
  __syncthreads();

  for (int kt = 0; kt < 18; ++kt) {
    const int cur = kt & 1, nxt = cur ^ 1;
    if (kt + 1 < 18) {
      const int k0 = (kt + 1) * 64;
      STAGE(smA, Mp, m0, nxt, k0)
      STAGE(smB, Wt, f0, nxt, k0)
    }
#pragma unroll
    for (int ks = 0; ks < 2; ++ks) {
      bf16x8 afr[4], bfr[4];
#pragma unroll
      for (int mt = 0; mt < 4; ++mt) {
        int row = wm + mt * 16 + arow;
        int c = (ks * 4 + aq) ^ (arow & 7);
        afr[mt] = *(const bf16x8*)&smA[cur][row * 64 + c * 8];
      }
#pragma unroll
      for (int ft = 0; ft < 4; ++ft) {
        int row = wf + ft * 16 + arow;
        int c = (ks * 4 + aq) ^ (arow & 7);
        bfr[ft] = *(const bf16x8*)&smB[cur][row * 64 + c * 8];
      }
#pragma unroll
      for (int mt = 0; mt < 4; ++mt)
#pragma unroll
        for (int ft = 0; ft < 4; ++ft)
          acc[mt][ft] = __builtin_amdgcn_mfma_f32_16x16x32_bf16(afr[mt], bfr[ft], acc[mt][ft], 0, 0, 0);
    }
    __syncthreads();
  }
#undef STAGE

  // Epilogue: D layout col(f)=lane&15, row(m)=quad*4+reg
  float bv[4];
#pragma unroll
  for (int ft = 0; ft < 4; ++ft)
    bv[ft] = bias[f0 + wf + ft * 16 + arow];
#pragma unroll
  for (int mt = 0; mt < 4; ++mt) {
#pragma unroll
    for (int ft = 0; ft < 4; ++ft) {
      const int f = f0 + wf + ft * 16 + arow;
#pragma unroll
      for (int r = 0; r < 4; ++r) {
        const int m = m0 + wm + mt * 16 + aq * 4 + r;
        Out[(size_t)m * FF + f] = acc[mt][ft][r] + bv[ft];
      }
    }
  }
}

extern "C" void kernel_launch(void* const* d_in, const int* in_sizes, int n_in,
                              void* d_out, int out_size, void* d_ws, size_t ws_size,
                              hipStream_t stream) {
  const float* X    = (const float*)d_in[0];
  const float* Off  = (const float*)d_in[1];
  const float* W    = (const float*)d_in[2];
  const float* bias = (const float*)d_in[3];
  float* Out = (float*)d_out;

  unsigned short* Wt = (unsigned short*)d_ws;          // 256*1152*2 = 589824 B
  unsigned short* Mp = Wt + (size_t)FF * KD;           // 32768*1152*2 = 75.5 MB

  wt_prep_kernel<<<(KD * FF) / 256, 256, 0, stream>>>(W, Wt);
  interp_kernel<<<(MTOT * NTAP * 8) / 256, 256, 0, stream>>>(X, Off, Mp);
  gemm_kernel<<<512, 256, 0, stream>>>(Mp, Wt, bias, Out);
}

// Round 4
// 147.547 us; speedup vs baseline: 1.2744x; 1.1064x over previous
//
#include <hip/hip_runtime.h>

#define HH 64
#define WW 64
#define CC 128
#define FF 256
#define NTAP 9
#define KD 1152   // NTAP*CC
#define MTOT 32768
#define XELEMS (8 * HH * WW * CC)   // 4194304

typedef __attribute__((ext_vector_type(8))) short bf16x8;
typedef __attribute__((ext_vector_type(4))) float floatx4;

// Faithful tap order from np.stack(np.meshgrid(arange(3),arange(3),indexing='ij')).reshape(-1,2)
__device__ __constant__ int c_iy[9] = {0,0,1,2,2,1,0,2,1};
__device__ __constant__ int c_ix[9] = {0,1,1,2,0,2,1,0,2};

__device__ inline unsigned short f2bf(float v) {
  union { float f; unsigned u; } c; c.f = v;
  unsigned r = (c.u + 0x7FFFu + ((c.u >> 16) & 1u)) >> 16;  // RNE
  return (unsigned short)r;
}
__device__ inline float bflo(unsigned u) {
  union { unsigned u; float f; } c; c.u = u << 16; return c.f;
}
__device__ inline float bfhi(unsigned u) {
  union { unsigned u; float f; } c; c.u = u & 0xFFFF0000u; return c.f;
}

// ---------------- Prep: X fp32 -> Xb bf16  AND  W [k][f] fp32 -> Wt [f][k] bf16 ----
__global__ void prep_kernel(const float* __restrict__ X, const float* __restrict__ W,
                            unsigned short* __restrict__ Xb, unsigned short* __restrict__ Wt) {
  const int blk = blockIdx.x;
  if (blk < XELEMS / (256 * 8)) {           // 2048 blocks: X convert, 8 elems/thread
    const int t = blk * 256 + threadIdx.x;
    const float4* src = (const float4*)(X + (size_t)t * 8);
    float4 a = src[0], b2 = src[1];
    bf16x8 o;
    o[0] = (short)f2bf(a.x);  o[1] = (short)f2bf(a.y);
    o[2] = (short)f2bf(a.z);  o[3] = (short)f2bf(a.w);
    o[4] = (short)f2bf(b2.x); o[5] = (short)f2bf(b2.y);
    o[6] = (short)f2bf(b2.z); o[7] = (short)f2bf(b2.w);
    *(bf16x8*)(Xb + (size_t)t * 8) = o;
  } else {                                  // 1152 blocks: W transpose
    const int idx = (blk - XELEMS / (256 * 8)) * 256 + threadIdx.x;  // 0..294911
    const int k = idx >> 8;
    const int f = idx & 255;
    Wt[f * KD + k] = f2bf(W[idx]);
  }
}

// ---------------- Kernel A: bilinear gather/interp producer (bf16 corners) --------
// 16 lanes per (pos, tap); lane c handles channels 8c..8c+7.
// Corner read per group = 256 B contiguous; Mp write per group = 256 B contiguous.
__global__ __launch_bounds__(256, 4) void interp_kernel(
    const unsigned short* __restrict__ Xb, const float* __restrict__ Off,
    unsigned short* __restrict__ Mp)
{
  const int blk = blockIdx.x;            // 0..18431
  const int b   = blk & 7;               // batch -> XCD locality
  const int bw  = blk >> 3;              // 0..2303
  const int tid = threadIdx.x;
  const int g   = tid >> 4;              // group 0..15
  const int c   = tid & 15;              // channel chunk (8 ch)
  const unsigned item = (unsigned)bw * 16u + g;   // 0..36863 = pos_local*9 + n
  const unsigned pos_local = item / 9u;
  const int n = (int)(item - pos_local * 9u);
  const int y = (int)(pos_local >> 6);
  const int x = (int)(pos_local & 63u);

  float2 off2 = *(const float2*)(Off + ((size_t)(b * HH + y) * WW + x) * (2 * NTAP) + 2 * n);
  float cy = (float)(y - 1 + c_iy[n]) + off2.x;
  float cx = (float)(x - 1 + c_ix[n]) + off2.y;
  cy = fminf(fmaxf(cy, 0.f), 63.f);
  cx = fminf(fmaxf(cx, 0.f), 63.f);
  float fy0 = floorf(cy), fy1 = ceilf(cy);
  float fx0 = floorf(cx), fx1 = ceilf(cx);
  int y0 = (int)fy0, y1 = (int)fy1, x0 = (int)fx0, x1 = (int)fx1;
  float fy = cy - fy0;
  float fx = cx - fx0;

  const unsigned short* xb = Xb + (size_t)b * (HH * WW * CC);
  const uint4 q00 = *(const uint4*)(xb + (y0 * WW + x0) * CC + c * 8); // lt
  const uint4 q10 = *(const uint4*)(xb + (y1 * WW + x0) * CC + c * 8); // rt (y1,x0)
  const uint4 q01 = *(const uint4*)(xb + (y0 * WW + x1) * CC + c * 8); // lb (y0,x1)
  const uint4 q11 = *(const uint4*)(xb + (y1 * WW + x1) * CC + c * 8); // rb

  const unsigned u00[4] = {q00.x, q00.y, q00.z, q00.w};
  const unsigned u10[4] = {q10.x, q10.y, q10.z, q10.w};
  const unsigned u01[4] = {q01.x, q01.y, q01.z, q01.w};
  const unsigned u11[4] = {q11.x, q11.y, q11.z, q11.w};

  unsigned outw[4];
#pragma unroll
  for (int j = 0; j < 4; ++j) {
    // low channel of the pair
    float v00 = bflo(u00[j]), v10 = bflo(u10[j]), v01 = bflo(u01[j]), v11 = bflo(u11[j]);
    float tx = v00 + (v10 - v00) * fy;
    float tb = v01 + (v11 - v01) * fy;
    unsigned short rlo = f2bf(tx + (tb - tx) * fx);
    // high channel of the pair
    v00 = bfhi(u00[j]); v10 = bfhi(u10[j]); v01 = bfhi(u01[j]); v11 = bfhi(u11[j]);
    tx = v00 + (v10 - v00) * fy;
    tb = v01 + (v11 - v01) * fy;
    unsigned short rhi = f2bf(tx + (tb - tx) * fx);
    outw[j] = (unsigned)rlo | ((unsigned)rhi << 16);
  }

  unsigned short* dst = Mp + (size_t)(b * 4096 + pos_local) * KD + n * CC + c * 8;
  *(uint4*)dst = make_uint4(outw[0], outw[1], outw[2], outw[3]);
}

// ---------------- Kernel B: GEMM 32768 x 1152 x 256 (bf16 -> fp32) ----------------
__global__ __launch_bounds__(256, 2) void gemm_kernel(
    const unsigned short* __restrict__ Mp, const unsigned short* __restrict__ Wt,
    const float* __restrict__ bias, float* __restrict__ Out)
{
  __shared__ unsigned short smA[2][128 * 64];
  __shared__ unsigned short smB[2][128 * 64];

  const int blk = blockIdx.x;            // 0..511
  const int mb = blk >> 1, fb = blk & 1;
  const int m0 = mb * 128, f0 = fb * 128;
  const int tid = threadIdx.x;
  const int wave = tid >> 6, lane = tid & 63;
  const int wm = (wave >> 1) * 64;
  const int wf = (wave & 1) * 64;
  const int arow = lane & 15, aq = lane >> 4;

  const int srow = tid >> 3;
  const int sch = tid & 7;

  floatx4 acc[4][4];
#pragma unroll
  for (int i2 = 0; i2 < 4; ++i2)
#pragma unroll
    for (int j2 = 0; j2 < 4; ++j2)
      acc[i2][j2] = (floatx4){0.f, 0.f, 0.f, 0.f};

#define STAGE(SM, SRC, ROW0, BUF, K0)                                              \
  {                                                                                \
    _Pragma("unroll")                                                              \
    for (int p = 0; p < 4; ++p) {                                                  \
      int row = p * 32 + srow;                                                     \
      int chp = sch ^ (row & 7);                                                   \
      const unsigned short* gp = (SRC) + (size_t)((ROW0) + row) * KD + (K0) + chp * 8; \
      unsigned short* l = &SM[BUF][row * 64 + sch * 8];                            \
      __builtin_amdgcn_global_load_lds(                                            \
          (const __attribute__((address_space(1))) unsigned int*)gp,               \
          (__attribute__((address_space(3))) unsigned int*)l, 16, 0, 0);           \
    }                                                                              \
  }

  STAGE(smA, Mp, m0, 0, 0)
  STAGE(smB, Wt, f0, 0, 0)
  __syncthreads();

  for (int kt = 0; kt < 18; ++kt) {
    const int cur = kt & 1, nxt = cur ^ 1;
    if (kt + 1 < 18) {
      const int k0 = (kt + 1) * 64;
      STAGE(smA, Mp, m0, nxt, k0)
      STAGE(smB, Wt, f0, nxt, k0)
    }
#pragma unroll
    for (int ks = 0; ks < 2; ++ks) {
      bf16x8 afr[4], bfr[4];
#pragma unroll
      for (int mt = 0; mt < 4; ++mt) {
        int row = wm + mt * 16 + arow;
        int cc2 = (ks * 4 + aq) ^ (arow & 7);
        afr[mt] = *(const bf16x8*)&smA[cur][row * 64 + cc2 * 8];
      }
#pragma unroll
      for (int ft = 0; ft < 4; ++ft) {
        int row = wf + ft * 16 + arow;
        int cc2 = (ks * 4 + aq) ^ (arow & 7);
        bfr[ft] = *(const bf16x8*)&smB[cur][row * 64 + cc2 * 8];
      }
#pragma unroll
      for (int mt = 0; mt < 4; ++mt)
#pragma unroll
        for (int ft = 0; ft < 4; ++ft)
          acc[mt][ft] = __builtin_amdgcn_mfma_f32_16x16x32_bf16(afr[mt], bfr[ft], acc[mt][ft], 0, 0, 0);
    }
    __syncthreads();
  }
#undef STAGE

  float bv[4];
#pragma unroll
  for (int ft = 0; ft < 4; ++ft)
    bv[ft] = bias[f0 + wf + ft * 16 + arow];
#pragma unroll
  for (int mt = 0; mt < 4; ++mt) {
#pragma unroll
    for (int ft = 0; ft < 4; ++ft) {
      const int f = f0 + wf + ft * 16 + arow;
#pragma unroll
      for (int r = 0; r < 4; ++r) {
        const int m = m0 + wm + mt * 16 + aq * 4 + r;
        Out[(size_t)m * FF + f] = acc[mt][ft][r] + bv[ft];
      }
    }
  }
}

extern "C" void kernel_launch(void* const* d_in, const int* in_sizes, int n_in,
                              void* d_out, int out_size, void* d_ws, size_t ws_size,
                              hipStream_t stream) {
  const float* X    = (const float*)d_in[0];
  const float* Off  = (const float*)d_in[1];
  const float* W    = (const float*)d_in[2];
  const float* bias = (const float*)d_in[3];
  float* Out = (float*)d_out;

  unsigned short* Wt = (unsigned short*)d_ws;                  // 294912 shorts
  unsigned short* Mp = Wt + (size_t)FF * KD;                   // 37748736 shorts (75.5 MB)
  unsigned short* Xb = Mp + (size_t)MTOT * KD;                 // 4194304 shorts (8.4 MB)

  prep_kernel<<<XELEMS / (256 * 8) + (KD * FF) / 256, 256, 0, stream>>>(X, W, Xb, Wt);
  interp_kernel<<<(MTOT * NTAP * 16) / 256, 256, 0, stream>>>(Xb, Off, Mp);
  gemm_kernel<<<512, 256, 0, stream>>>(Mp, Wt, bias, Out);
}